// Round 1
// baseline (119.036 us; speedup 1.0000x reference)
//
#include <hip/hip_runtime.h>

// CenterLoss: loss = mean_b clip(||x_b - centers[labels[b]]||^2, 1e-12, 1e12)
//             + (C-1)*1e-12   (faithful replication of clipping the masked zeros)
//
// x:       (8192, 2048) f32
// labels:  (8192,)      int
// centers: (4096, 2048) f32
// out:     scalar f32

#define BATCH 8192
#define FEAT  2048
#define NCLS  4096
#define BLK   256

__global__ void cl_init(float* ws) { ws[0] = 0.0f; }

__global__ void __launch_bounds__(BLK)
cl_dist(const float* __restrict__ x,
        const int* __restrict__ labels,
        const float* __restrict__ centers,
        float* __restrict__ ws) {
    const int b   = blockIdx.x;
    const int tid = threadIdx.x;

    const int lbl = labels[b];

    const float4* __restrict__ xr =
        reinterpret_cast<const float4*>(x + (size_t)b * FEAT);
    const float4* __restrict__ cr =
        reinterpret_cast<const float4*>(centers + (size_t)lbl * FEAT);

    float acc = 0.0f;
#pragma unroll
    for (int i = 0; i < FEAT / 4 / BLK; ++i) {   // 2 iterations
        const int idx = tid + i * BLK;
        const float4 xv = xr[idx];
        const float4 cv = cr[idx];
        float d0 = xv.x - cv.x;
        float d1 = xv.y - cv.y;
        float d2 = xv.z - cv.z;
        float d3 = xv.w - cv.w;
        acc += d0 * d0 + d1 * d1 + d2 * d2 + d3 * d3;
    }

    // wave (64-lane) reduction
#pragma unroll
    for (int off = 32; off > 0; off >>= 1)
        acc += __shfl_down(acc, off, 64);

    __shared__ float s[BLK / 64];
    const int wid  = tid >> 6;
    const int lane = tid & 63;
    if (lane == 0) s[wid] = acc;
    __syncthreads();

    if (tid == 0) {
        float d = s[0] + s[1] + s[2] + s[3];
        // per-sample clip BEFORE summing across samples
        d = fminf(fmaxf(d, 1e-12f), 1e12f);
        atomicAdd(ws, d);
    }
}

__global__ void cl_final(const float* __restrict__ ws, float* __restrict__ out) {
    // masked-zero entries: (BATCH*NCLS - BATCH) * 1e-12 / BATCH = (NCLS-1)*1e-12
    out[0] = ws[0] / (float)BATCH + (float)(NCLS - 1) * 1e-12f;
}

extern "C" void kernel_launch(void* const* d_in, const int* in_sizes, int n_in,
                              void* d_out, int out_size, void* d_ws, size_t ws_size,
                              hipStream_t stream) {
    const float* x       = (const float*)d_in[0];
    const int*   labels  = (const int*)d_in[1];
    const float* centers = (const float*)d_in[2];
    float* out = (float*)d_out;
    float* ws  = (float*)d_ws;

    cl_init<<<1, 1, 0, stream>>>(ws);
    cl_dist<<<BATCH, BLK, 0, stream>>>(x, labels, centers, ws);
    cl_final<<<1, 1, 0, stream>>>(ws, out);
}

// Round 2
// 25.952 us; speedup vs baseline: 4.5868x; 4.5868x over previous
//
#include <hip/hip_runtime.h>

// CenterLoss: loss = mean_b clip(||x_b - centers[labels[b]]||^2, 1e-12, 1e12)
//             + (C-1)*1e-12   (faithful replication of clipping the masked zeros)
//
// x:       (8192, 2048) f32
// labels:  (8192,)      int
// centers: (4096, 2048) f32
// out:     scalar f32
//
// Stage 1: one wave per sample (4 samples/block), atomic-free partial sums.
// Stage 2: single block reduces the 2048 block partials.

#define BATCH 8192
#define FEAT  2048
#define NCLS  4096
#define BLK   256
#define WAVES_PER_BLK (BLK / 64)              // 4
#define NPART (BATCH / WAVES_PER_BLK)         // 2048 blocks / partials

__global__ void __launch_bounds__(BLK)
cl_dist(const float* __restrict__ x,
        const int* __restrict__ labels,
        const float* __restrict__ centers,
        float* __restrict__ part) {
    const int tid  = threadIdx.x;
    const int wid  = tid >> 6;
    const int lane = tid & 63;
    const int b    = blockIdx.x * WAVES_PER_BLK + wid;   // sample for this wave

    const int lbl = labels[b];                           // wave-uniform -> s_load

    const float4* __restrict__ xr =
        reinterpret_cast<const float4*>(x + (size_t)b * FEAT);
    const float4* __restrict__ cr =
        reinterpret_cast<const float4*>(centers + (size_t)lbl * FEAT);

    // 2048 floats / 64 lanes = 32 floats = 8 float4 per lane, per operand.
    // Fully unrolled -> 16 outstanding 16B loads per lane (deep MLP).
    float acc0 = 0.0f, acc1 = 0.0f;
#pragma unroll
    for (int j = 0; j < FEAT / 4 / 64; ++j) {            // 8 iterations
        const int idx = lane + j * 64;
        const float4 xv = xr[idx];
        const float4 cv = cr[idx];
        const float d0 = xv.x - cv.x;
        const float d1 = xv.y - cv.y;
        const float d2 = xv.z - cv.z;
        const float d3 = xv.w - cv.w;
        acc0 += d0 * d0 + d1 * d1;
        acc1 += d2 * d2 + d3 * d3;
    }
    float acc = acc0 + acc1;

    // wave (64-lane) reduction
#pragma unroll
    for (int off = 32; off > 0; off >>= 1)
        acc += __shfl_down(acc, off, 64);

    __shared__ float s[WAVES_PER_BLK];
    if (lane == 0) {
        // per-sample clip BEFORE summing across samples
        s[wid] = fminf(fmaxf(acc, 1e-12f), 1e12f);
    }
    __syncthreads();

    if (tid == 0)
        part[blockIdx.x] = s[0] + s[1] + s[2] + s[3];
}

__global__ void __launch_bounds__(BLK)
cl_final(const float* __restrict__ part, float* __restrict__ out) {
    const int tid = threadIdx.x;
    float acc = 0.0f;
#pragma unroll
    for (int j = 0; j < NPART / BLK; ++j)                // 8 iterations
        acc += part[tid + j * BLK];

#pragma unroll
    for (int off = 32; off > 0; off >>= 1)
        acc += __shfl_down(acc, off, 64);

    __shared__ float s[BLK / 64];
    const int wid  = tid >> 6;
    const int lane = tid & 63;
    if (lane == 0) s[wid] = acc;
    __syncthreads();

    if (tid == 0) {
        const float total = s[0] + s[1] + s[2] + s[3];
        // masked-zero entries: (BATCH*NCLS - BATCH) * 1e-12 / BATCH
        out[0] = total / (float)BATCH + (float)(NCLS - 1) * 1e-12f;
    }
}

extern "C" void kernel_launch(void* const* d_in, const int* in_sizes, int n_in,
                              void* d_out, int out_size, void* d_ws, size_t ws_size,
                              hipStream_t stream) {
    const float* x       = (const float*)d_in[0];
    const int*   labels  = (const int*)d_in[1];
    const float* centers = (const float*)d_in[2];
    float* out  = (float*)d_out;
    float* part = (float*)d_ws;   // 2048 floats, fully overwritten every call

    cl_dist<<<NPART, BLK, 0, stream>>>(x, labels, centers, part);
    cl_final<<<1, BLK, 0, stream>>>(part, out);
}